// Round 1
// baseline (449.067 us; speedup 1.0000x reference)
//
#include <hip/hip_runtime.h>

// Problem constants (from reference)
#define Nn 1024
#define Hh 96
#define Ee 16384
#define IN_K 9       // IN_RAW-1
#define IN_STRIDE 10 // x is (N, 10), we use first 9 cols
#define NH (Nn * Hh)
#define XS 128       // padded row stride for x-like (N,96) buffers
#define SLOTS 64     // CSR bucket capacity (Poisson(16) degree; P(>64) ~ 0)
#define NBLK 256     // persistent grid: 1 block/CU guaranteed by launch_bounds

__device__ __forceinline__ float sigf(float v) {
    return __builtin_amdgcn_rcpf(1.0f + __expf(-v));
}
__device__ __forceinline__ float tanhfast(float v) {
    float e = __expf(2.0f * v);
    return (e - 1.0f) * __builtin_amdgcn_rcpf(e + 1.0f);
}
__device__ __forceinline__ float leakyf(float v) {
    return v >= 0.0f ? v : 0.01f * v;
}

struct Params {
    const float* x_in; const int* ei; const int* adj;
    const float* W_init; const float* b_init;
    const float* W_ggc; const float* W_ih; const float* W_hh;
    const float* b_ih; const float* b_hh;
    const float* Wa1; const float* ba1; const float* Wa2; const float* ba2;
    const float* Wo1; const float* bo1; const float* Wo2; const float* bo2;
    const float* Wp1; const float* bp1; const float* Wp2; const float* bp2;
    float* out;
    float* xA; float* xB; float* xC; float* Ei; float* EjT;
    float* Wt_hh; float* Wf; float* Wt_a1i; float* Wt_a1j;
    float* Wt_o1; float* Wt_o2;
    int* deg; int* bucket; int* bar;
};

// LDS union across phases. Max member = gru struct: 53760 B (< 64 KB static).
union Shm {
    struct {                        // gru phase
        float Pm[4][Hh];            // per-row gather mean
        float Xr[4][Hh];            // per-row x
        float Xo[4][Hh];            // per-row GRU output
        float red[4][4][6][Hh];     // [kquarter][row][gate][h]
        float redp[4][4][2][Hh];    // attn-proj partials
    } g;
    struct {                        // attn phase
        float sm[7168];             // coeffs (4x1024) @0 + partials @4096
        float hd[3][4][Hh];         // fused head temporaries (u1 only)
    } a;
    int ldeg[Nn];                   // edges phase (block 0)
};

// Grid barrier: all NBLK blocks are co-resident (grid == #CUs, launch_bounds
// caps VGPR<=128 so 1 block/CU always fits; LDS 53.8KB -> capacity >= 1).
// Device-scope release/acquire per Guideline 16 (cross-XCD L2 non-coherence).
__device__ __forceinline__ void gsync(int* bar, int idx) {
    __syncthreads();                     // compiler drains vmcnt before barrier
    if (threadIdx.x == 0) {
        __threadfence();                 // agent-scope release of prior stores
        __hip_atomic_fetch_add(bar + idx, 1, __ATOMIC_ACQ_REL,
                               __HIP_MEMORY_SCOPE_AGENT);
        while (__hip_atomic_load(bar + idx, __ATOMIC_ACQUIRE,
                                 __HIP_MEMORY_SCOPE_AGENT) < NBLK) {
            __builtin_amdgcn_s_sleep(1);
        }
    }
    __syncthreads();
}

// ---------------- gru phase: 4 rows/block, weight-register-sharing ---------
// Active threads: 384 = (h in [0,96)) x (q = k-quarter in [0,4)).
// Each (h,q) thread loads 6 weight values per k ONCE and accumulates all
// 4 rows -> 4x less Wf/Wt_hh L2 traffic than the 1-row/block version.
__device__ __forceinline__ void gru_phase(const Params& p, Shm& sh,
                                          const float* xin, float* xout)
{
    int tid = threadIdx.x;
    int i0 = blockIdx.x * 4;
    int h = tid % Hh;
    int q = tid / Hh;          // 0..3 for tid<384
    bool act = tid < 4 * Hh;

    // A: gather + x-row load; thread (h,q) owns (row q, col h) fully
    if (act) {
        int n = i0 + q;
        int d = p.deg[n];
        int dc = d < SLOTS ? d : SLOTS;
        const int* bk = p.bucket + n * SLOTS;
        float acc = 0.0f;
        for (int s = 0; s < dc; ++s)
            acc += xin[bk[s] * XS + h];
        float inv = __builtin_amdgcn_rcpf(fmaxf((float)d, 1.0f));
        sh.g.Pm[q][h] = acc * inv;
        sh.g.Xr[q][h] = xin[n * XS + h];
    }
    __syncthreads();

    // B: GRU gate dots, k-quarter per thread, all 4 rows in registers
    if (act) {
        float g0[4], g1[4], g2[4], g3[4], g4[4], g5[4];
#pragma unroll
        for (int r = 0; r < 4; ++r) {
            g0[r] = g1[r] = g2[r] = g3[r] = g4[r] = g5[r] = 0.0f;
        }
        const float* pf = p.Wf + h;
        const float* ph = p.Wt_hh + h;
        int k0 = q * 24;
#pragma unroll 4
        for (int k = k0; k < k0 + 24; ++k) {
            int o = k * 288;
            float w0 = pf[o], w1 = pf[o + 96], w2 = pf[o + 192];
            float u0 = ph[o], u1 = ph[o + 96], u2 = ph[o + 192];
#pragma unroll
            for (int r = 0; r < 4; ++r) {
                float a  = sh.g.Pm[r][k];   // LDS broadcast
                float xv = sh.g.Xr[r][k];   // LDS broadcast
                g0[r] += a * w0;  g1[r] += a * w1;  g2[r] += a * w2;
                g3[r] += xv * u0; g4[r] += xv * u1; g5[r] += xv * u2;
            }
        }
#pragma unroll
        for (int r = 0; r < 4; ++r) {
            sh.g.red[q][r][0][h] = g0[r];
            sh.g.red[q][r][1][h] = g1[r];
            sh.g.red[q][r][2][h] = g2[r];
            sh.g.red[q][r][3][h] = g3[r];
            sh.g.red[q][r][4][h] = g4[r];
            sh.g.red[q][r][5][h] = g5[r];
        }
    }
    __syncthreads();

    // C: reduce quarters + gate math; thread (h,q) finishes row q
    if (act) {
        int n = i0 + q;
        float gir = p.b_ih[h], giz = p.b_ih[Hh + h], gin = p.b_ih[2 * Hh + h];
        float ghr = p.b_hh[h], ghz = p.b_hh[Hh + h], ghn = p.b_hh[2 * Hh + h];
#pragma unroll
        for (int qq = 0; qq < 4; ++qq) {
            gir += sh.g.red[qq][q][0][h];
            giz += sh.g.red[qq][q][1][h];
            gin += sh.g.red[qq][q][2][h];
            ghr += sh.g.red[qq][q][3][h];
            ghz += sh.g.red[qq][q][4][h];
            ghn += sh.g.red[qq][q][5][h];
        }
        float rr  = sigf(gir + ghr);
        float z   = sigf(giz + ghz);
        float nn2 = tanhfast(gin + rr * ghn);
        float xo  = (1.0f - z) * nn2 + z * sh.g.Xr[q][h];
        xout[n * XS + h] = xo;
        sh.g.Xo[q][h] = xo;
    }
    __syncthreads();

    // D: attention projections (same weight-sharing scheme)
    if (act) {
        const float* wi = p.Wt_a1i + h;
        const float* wj = p.Wt_a1j + h;
        float pa[4] = {0, 0, 0, 0}, pb[4] = {0, 0, 0, 0};
        int k0 = q * 24;
#pragma unroll 4
        for (int k = k0; k < k0 + 24; ++k) {
            float wik = wi[k * 96], wjk = wj[k * 96];
#pragma unroll
            for (int r = 0; r < 4; ++r) {
                float xv = sh.g.Xo[r][k];   // LDS broadcast
                pa[r] += xv * wik;
                pb[r] += xv * wjk;
            }
        }
#pragma unroll
        for (int r = 0; r < 4; ++r) {
            sh.g.redp[q][r][0][h] = pa[r];
            sh.g.redp[q][r][1][h] = pb[r];
        }
    }
    __syncthreads();
    if (act) {
        int n = i0 + q;
        float a = sh.g.redp[0][q][0][h] + sh.g.redp[1][q][0][h]
                + sh.g.redp[2][q][0][h] + sh.g.redp[3][q][0][h];
        float b = sh.g.redp[0][q][1][h] + sh.g.redp[1][q][1][h]
                + sh.g.redp[2][q][1][h] + sh.g.redp[3][q][1][h];
        p.Ei[n * Hh + h]  = __expf(-(a + p.ba1[h]));
        p.EjT[h * Nn + n] = __expf(-b);
    }
    // no trailing block sync needed: a grid sync follows
}

// ---------------- attn phases: ported verbatim from attn_kernel_u0/u1 ------
__device__ __forceinline__ void attn_coeff(const Params& p, Shm& sh,
                                           const float* xB)
{
    int tid = threadIdx.x;
    int i0 = blockIdx.x * 4;
    {
        int j = tid;
        int m0 = p.adj[(i0 + 0) * Nn + j];
        int m1 = p.adj[(i0 + 1) * Nn + j];
        int m2 = p.adj[(i0 + 2) * Nn + j];
        int m3 = p.adj[(i0 + 3) * Nn + j];
        const float* e0 = p.Ei + i0 * Hh;   // uniform base -> s_load path
        float s0 = 0.f, s1 = 0.f, s2 = 0.f, s3 = 0.f;
#pragma unroll 8
        for (int k = 0; k < Hh; ++k) {
            float e = p.EjT[k * Nn + j];
            float wk = p.Wa2[k];            // s_load
            s0 += __builtin_amdgcn_rcpf(fmaf(e0[k], e, 1.0f)) * wk;
            s1 += __builtin_amdgcn_rcpf(fmaf(e0[96 + k], e, 1.0f)) * wk;
            s2 += __builtin_amdgcn_rcpf(fmaf(e0[192 + k], e, 1.0f)) * wk;
            s3 += __builtin_amdgcn_rcpf(fmaf(e0[288 + k], e, 1.0f)) * wk;
        }
        float b2 = p.ba2[0];
        sh.a.sm[0 * Nn + j] = (m0 == 1) ? sigf(s0 + b2) : 0.0f;
        sh.a.sm[1 * Nn + j] = (m1 == 1) ? sigf(s1 + b2) : 0.0f;
        sh.a.sm[2 * Nn + j] = (m2 == 1) ? sigf(s2 + b2) : 0.0f;
        sh.a.sm[3 * Nn + j] = (m3 == 1) ? sigf(s3 + b2) : 0.0f;
    }
    __syncthreads();
    {
        int q = tid >> 7;
        int h = tid & 127;
        if (h < Hh) {
            int jb = q * 128;
            const float* xc = xB + jb * XS + h;
            const float* c0 = sh.a.sm + 0 * Nn + jb;
            const float* c1 = sh.a.sm + 1 * Nn + jb;
            const float* c2 = sh.a.sm + 2 * Nn + jb;
            const float* c3 = sh.a.sm + 3 * Nn + jb;
            float a0 = 0.f, a1 = 0.f, a2 = 0.f, a3 = 0.f;
#pragma unroll 4
            for (int j = 0; j < 128; ++j) {
                float xv = xc[j * XS];
                a0 += c0[j] * xv;
                a1 += c1[j] * xv;
                a2 += c2[j] * xv;
                a3 += c3[j] * xv;
            }
            sh.a.sm[4096 + ((q * 4 + 0) * Hh) + h] = a0;
            sh.a.sm[4096 + ((q * 4 + 1) * Hh) + h] = a1;
            sh.a.sm[4096 + ((q * 4 + 2) * Hh) + h] = a2;
            sh.a.sm[4096 + ((q * 4 + 3) * Hh) + h] = a3;
        }
    }
    __syncthreads();
}

__device__ __forceinline__ void attn_tail_u0(const Params& p, Shm& sh,
                                             float* xOut)
{
    int tid = threadIdx.x;
    int i0 = blockIdx.x * 4;
    if (tid < 4 * Hh) {
        int r = tid / Hh, h = tid - r * Hh;
        float v = 0.f;
#pragma unroll
        for (int q = 0; q < 8; ++q)
            v += sh.a.sm[4096 + ((q * 4 + r) * Hh) + h];
        xOut[(i0 + r) * XS + h] = v;
    }
}

__device__ __forceinline__ void attn_tail_u1(const Params& p, Shm& sh)
{
    int tid = threadIdx.x;
    int i0 = blockIdx.x * 4;
    if (tid < 4 * Hh) {
        int r = tid / Hh, h = tid - r * Hh;
        float v = 0.f;
#pragma unroll
        for (int q = 0; q < 8; ++q)
            v += sh.a.sm[4096 + ((q * 4 + r) * Hh) + h];
        sh.a.hd[0][r][h] = v;
    }
    __syncthreads();
    if (tid < 4 * Hh) {
        int r = tid / Hh, h = tid - r * Hh;
        const float* w = p.Wt_o1 + h;
        const float* xr = sh.a.hd[0][r];
        float acc = p.bo1[h];
        for (int k = 0; k < Hh; ++k) acc += xr[k] * w[k * 96];
        sh.a.hd[1][r][h] = leakyf(acc);
    }
    __syncthreads();
    if (tid < 4 * Hh) {
        int r = tid / Hh, h = tid - r * Hh;
        const float* w = p.Wt_o2 + h;
        const float* xr = sh.a.hd[1][r];
        float acc = p.bo2[h];
        for (int k = 0; k < Hh; ++k) acc += xr[k] * w[k * 96];
        sh.a.hd[2][r][h] = leakyf(acc);
    }
    __syncthreads();
    if (tid < 8) {
        int r = tid >> 1, which = tid & 1;
        const float* wp = which ? p.Wp2 : p.Wp1;
        const float* xr = sh.a.hd[2][r];
        float acc = 0.f;
        for (int k = 0; k < Hh; ++k) acc += xr[k] * wp[k];
        float b = which ? p.bp2[0] : p.bp1[0];
        p.out[which * Nn + i0 + r] = sigf(acc + b);
    }
}

// ---------------- fused persistent kernel ----------------------------------
__global__ __launch_bounds__(1024) void fused_kernel(Params p)
{
    __shared__ Shm sh;
    int tid = threadIdx.x;
    int blk = blockIdx.x;

    // ---- P0: block 0 = edges via LDS histogram; blocks 1..255 = setup ----
    if (blk == 0) {
        sh.ldeg[tid] = 0;               // tid < 1024 always
        __syncthreads();
        for (int e = tid; e < Ee; e += 1024) {
            int src = p.ei[e];
            int tgt = p.ei[Ee + e];
            int slot = atomicAdd(&sh.ldeg[tgt], 1);
            if (slot < SLOTS) p.bucket[tgt * SLOTS + slot] = src;
        }
        __syncthreads();
        p.deg[tid] = sh.ldeg[tid];
    } else {
        int gt = (blk - 1) * 1024 + tid;    // [0, 261120) covers all work
        if (gt < 64512) {   // transposes: Wt_hh 27648 + 4x9216
            int idx = gt;
            if (idx < 27648) {
                int k = idx / 288, c = idx % 288;
                p.Wt_hh[idx] = p.W_hh[c * 96 + k];
            } else if ((idx -= 27648) < 9216) {
                int k = idx / 96, h2 = idx % 96;
                p.Wt_a1i[idx] = p.Wa1[h2 * 192 + k];
            } else if ((idx -= 9216) < 9216) {
                int k = idx / 96, h2 = idx % 96;
                p.Wt_a1j[idx] = p.Wa1[h2 * 192 + 96 + k];
            } else if ((idx -= 9216) < 9216) {
                int k = idx / 96, j = idx % 96;
                p.Wt_o1[idx] = p.Wo1[j * 96 + k];
            } else {
                idx -= 9216;
                int k = idx / 96, j = idx % 96;
                p.Wt_o2[idx] = p.Wo2[j * 96 + k];
            }
        }
        if (gt < 27648) {   // Wf[k][c] = sum_j W_ggc[k][j] * W_ih[c][j]
            int k = gt / 288, c = gt % 288;
            const float* g = p.W_ggc + k * 96;
            const float* w = p.W_ih + c * 96;
            float acc = 0.0f;
            for (int j = 0; j < 96; ++j) acc += g[j] * w[j];
            p.Wf[gt] = acc;
        }
        if (gt < NH) {      // init linear
            int n = gt / Hh, j = gt - n * Hh;
            const float* xr = p.x_in + n * IN_STRIDE;
            const float* wr = p.W_init + j * IN_K;
            float acc = p.b_init[j];
#pragma unroll
            for (int k = 0; k < IN_K; ++k) acc += xr[k] * wr[k];
            p.xA[n * XS + j] = leakyf(acc);
        }
    }
    gsync(p.bar, 0);

    // ---- unroll 0: xA -> xB -> xC ----
    gru_phase(p, sh, p.xA, p.xB);
    gsync(p.bar, 1);
    attn_coeff(p, sh, p.xB);
    attn_tail_u0(p, sh, p.xC);
    gsync(p.bar, 2);

    // ---- unroll 1: xC -> xB -> (fused head) -> out ----
    gru_phase(p, sh, p.xC, p.xB);
    gsync(p.bar, 3);
    attn_coeff(p, sh, p.xB);
    attn_tail_u1(p, sh);
}

extern "C" void kernel_launch(void* const* d_in, const int* in_sizes, int n_in,
                              void* d_out, int out_size, void* d_ws, size_t ws_size,
                              hipStream_t stream)
{
    const float* x_in   = (const float*)d_in[0];
    const int*   ei     = (const int*)d_in[1];
    const int*   adj    = (const int*)d_in[2];
    const float* W_init = (const float*)d_in[3];
    const float* b_init = (const float*)d_in[4];
    const float* W_ggc  = (const float*)d_in[5];
    const float* W_ih   = (const float*)d_in[6];
    const float* W_hh   = (const float*)d_in[7];
    const float* b_ih   = (const float*)d_in[8];
    const float* b_hh   = (const float*)d_in[9];
    const float* Wa1    = (const float*)d_in[10];
    const float* ba1    = (const float*)d_in[11];
    const float* Wa2    = (const float*)d_in[12];
    const float* ba2    = (const float*)d_in[13];
    const float* Wo1    = (const float*)d_in[14];
    const float* bo1    = (const float*)d_in[15];
    const float* Wo2    = (const float*)d_in[16];
    const float* bo2    = (const float*)d_in[17];
    const float* Wp1    = (const float*)d_in[18];
    const float* bp1    = (const float*)d_in[19];
    const float* Wp2    = (const float*)d_in[20];
    const float* bp2    = (const float*)d_in[21];
    float* out = (float*)d_out;

    // workspace layout, ~3 MB
    float* ws     = (float*)d_ws;
    float* xA     = ws;                     // (N, XS)
    float* xB     = xA + Nn * XS;           // (N, XS)
    float* xC     = xB + Nn * XS;           // (N, XS)
    float* Ei     = xC + Nn * XS;           // (N, 96)
    float* EjT    = Ei + NH;                // (96, N)
    float* Wt_hh  = EjT + NH;               // 96*288
    float* Wf     = Wt_hh + 27648;          // 96*288
    float* Wt_a1i = Wf + 27648;             // 96*96
    float* Wt_a1j = Wt_a1i + 9216;
    float* Wt_o1  = Wt_a1j + 9216;
    float* Wt_o2  = Wt_o1 + 9216;
    int*   deg    = (int*)(Wt_o2 + 9216);   // (N)
    int*   bucket = deg + Nn;               // (N, SLOTS)
    int*   bar    = bucket + Nn * SLOTS;    // 4 grid-barrier counters

    hipMemsetAsync(bar, 0, 4 * sizeof(int), stream);

    Params p;
    p.x_in = x_in; p.ei = ei; p.adj = adj;
    p.W_init = W_init; p.b_init = b_init;
    p.W_ggc = W_ggc; p.W_ih = W_ih; p.W_hh = W_hh;
    p.b_ih = b_ih; p.b_hh = b_hh;
    p.Wa1 = Wa1; p.ba1 = ba1; p.Wa2 = Wa2; p.ba2 = ba2;
    p.Wo1 = Wo1; p.bo1 = bo1; p.Wo2 = Wo2; p.bo2 = bo2;
    p.Wp1 = Wp1; p.bp1 = bp1; p.Wp2 = Wp2; p.bp2 = bp2;
    p.out = out;
    p.xA = xA; p.xB = xB; p.xC = xC; p.Ei = Ei; p.EjT = EjT;
    p.Wt_hh = Wt_hh; p.Wf = Wf; p.Wt_a1i = Wt_a1i; p.Wt_a1j = Wt_a1j;
    p.Wt_o1 = Wt_o1; p.Wt_o2 = Wt_o2;
    p.deg = deg; p.bucket = bucket; p.bar = bar;

    fused_kernel<<<NBLK, 1024, 0, stream>>>(p);
}

// Round 3
// 283.035 us; speedup vs baseline: 1.5866x; 1.5866x over previous
//
#include <hip/hip_runtime.h>

// Problem constants (from reference)
#define Nn 1024
#define Hh 96
#define Ee 16384
#define IN_K 9       // IN_RAW-1
#define IN_STRIDE 10 // x is (N, 10), we use first 9 cols
#define NH (Nn * Hh)
#define XS 128       // padded row stride for x-like (N,96) buffers
#define SLOTS 64     // CSR bucket capacity (Poisson(16) degree; P(>64) ~ 0)
#define NBLK 256     // persistent grid: co-residency guaranteed (16 waves/blk)

__device__ __forceinline__ float sigf(float v) {
    return __builtin_amdgcn_rcpf(1.0f + __expf(-v));
}
__device__ __forceinline__ float tanhfast(float v) {
    float e = __expf(2.0f * v);
    return (e - 1.0f) * __builtin_amdgcn_rcpf(e + 1.0f);
}
__device__ __forceinline__ float leakyf(float v) {
    return v >= 0.0f ? v : 0.01f * v;
}

struct Params {
    const float* x_in; const int* ei; const int* adj;
    const float* W_init; const float* b_init;
    const float* W_ggc; const float* W_ih; const float* W_hh;
    const float* b_ih; const float* b_hh;
    const float* Wa1; const float* ba1; const float* Wa2; const float* ba2;
    const float* Wo1; const float* bo1; const float* Wo2; const float* bo2;
    const float* Wp1; const float* bp1; const float* Wp2; const float* bp2;
    float* out;
    float* xA; float* xB; float* xC; float* Ei; float* EjT;
    float* Wt_hh; float* Wf; float* Wt_a1i; float* Wt_a1j;
    float* Wt_o1; float* Wt_o2;
    int* deg; int* bucket; int* bar;
};

// LDS union across phases. Max member = attn struct: 33280 B.
union Shm {
    struct {                        // gru phase
        float Pg[2][4][Hh];         // gather split-2 partials
        float Pm[4][Hh];            // per-row gather mean
        float Xr[4][Hh];            // per-row x
        float Xo[4][Hh];            // per-row GRU output
        float gd[6][4][Hh];         // full-K gate dots [gate][row][h]
        float redp[2][4][4][Hh];    // proj partials [w][q][row][h]
    } g;
    struct {                        // attn phase
        float sm[7168];             // coeffs (4x1024) @0 + partials @4096
        float hd[3][4][Hh];         // fused head temporaries (u1 only)
    } a;
};

// Grid barrier. Round-1 lesson: polling with ACQUIRE emits buffer_inv
// (L1 + per-XCD L2 flash-invalidate) EVERY iteration — spinning blocks
// continuously wiped the L2 of XCD-mates still computing (375us, 16MB
// refetch). Now: one RELEASE on arrival; spin on a RELAXED agent load
// (sc1, L2-bypassing, no invalidate); every 16th poll is an ACQUIRE as a
// forward-progress guarantee (deadlock-proof even if a relaxed load could
// ever be served stale); one final ACQUIRE before proceeding. L1 is
// per-CU and shared by the whole block, so thread 0's acquire suffices.
__device__ __forceinline__ void gsync(int* bar, int idx) {
    __syncthreads();                 // drains vmcnt -> stores in L2
    if (threadIdx.x == 0) {
        __hip_atomic_fetch_add(bar + idx, 1, __ATOMIC_RELEASE,
                               __HIP_MEMORY_SCOPE_AGENT);
        int it = 0;
        for (;;) {
            int v = __hip_atomic_load(bar + idx, __ATOMIC_RELAXED,
                                      __HIP_MEMORY_SCOPE_AGENT);
            if (v >= NBLK) break;
            if ((++it & 15) == 0) {
                v = __hip_atomic_load(bar + idx, __ATOMIC_ACQUIRE,
                                      __HIP_MEMORY_SCOPE_AGENT);
                if (v >= NBLK) break;
            }
            __builtin_amdgcn_s_sleep(8);
        }
        (void)__hip_atomic_load(bar + idx, __ATOMIC_ACQUIRE,
                                __HIP_MEMORY_SCOPE_AGENT);
    }
    __syncthreads();
}

// ---------------- gru phase: 4 rows/block ----------------------------------
// Gather 768 thr (12 waves), gate dots 576 thr (9 waves) computing FULL-K
// dots (no k-split reduction round-trip), projections 768 thr.
// Weight-register-sharing across the 4 rows: each weight load feeds 4 fma.
__device__ __forceinline__ void gru_phase(const Params& p, Shm& sh,
                                          const float* xin, float* xout)
{
    int tid = threadIdx.x;
    int i0 = blockIdx.x * 4;

    // A: gather, 768 threads (s2, r, h); thread sums slots s2, s2+2, ...
    if (tid < 768) {
        int h = tid % Hh;
        int rr = (tid / Hh) & 3;
        int s2 = tid / 384;
        int n = i0 + rr;
        int d = p.deg[n];
        int dc = d < SLOTS ? d : SLOTS;
        const int* bk = p.bucket + n * SLOTS;
        float acc = 0.0f;
        for (int s = s2; s < dc; s += 2)
            acc += xin[bk[s] * XS + h];
        sh.g.Pg[s2][rr][h] = acc;
        if (s2 == 0) sh.g.Xr[rr][h] = xin[n * XS + h];
    }
    __syncthreads();
    if (tid < 384) {   // combine -> mean
        int h = tid % Hh, rr = tid / Hh;
        float inv = __builtin_amdgcn_rcpf(fmaxf((float)p.deg[i0 + rr], 1.0f));
        sh.g.Pm[rr][h] = (sh.g.Pg[0][rr][h] + sh.g.Pg[1][rr][h]) * inv;
    }
    __syncthreads();

    // B: 6 gate dots, 576 threads (gate, h), full K=96, 4 rows in registers
    if (tid < 576) {
        int h = tid % Hh;
        int g = tid / Hh;              // 0..2: i-path (Wf/Pm), 3..5: h-path
        bool ipath = g < 3;
        int gc = ipath ? g : g - 3;
        const float* W = (ipath ? p.Wf : p.Wt_hh) + gc * 96 + h;
        const float (*src)[Hh] = ipath ? sh.g.Pm : sh.g.Xr;
        float a0 = 0.f, a1 = 0.f, a2 = 0.f, a3 = 0.f;
#pragma unroll 8
        for (int k = 0; k < 96; ++k) {
            float w = W[k * 288];
            a0 += src[0][k] * w;
            a1 += src[1][k] * w;
            a2 += src[2][k] * w;
            a3 += src[3][k] * w;
        }
        sh.g.gd[g][0][h] = a0;
        sh.g.gd[g][1][h] = a1;
        sh.g.gd[g][2][h] = a2;
        sh.g.gd[g][3][h] = a3;
    }
    __syncthreads();

    // C: gate math, 384 threads (r, h)
    if (tid < 384) {
        int h = tid % Hh, rr = tid / Hh;
        float gir = p.b_ih[h]        + sh.g.gd[0][rr][h];
        float giz = p.b_ih[96 + h]   + sh.g.gd[1][rr][h];
        float gin = p.b_ih[192 + h]  + sh.g.gd[2][rr][h];
        float ghr = p.b_hh[h]        + sh.g.gd[3][rr][h];
        float ghz = p.b_hh[96 + h]   + sh.g.gd[4][rr][h];
        float ghn = p.b_hh[192 + h]  + sh.g.gd[5][rr][h];
        float r_  = sigf(gir + ghr);
        float z   = sigf(giz + ghz);
        float nn2 = tanhfast(gin + r_ * ghn);
        float xo  = (1.0f - z) * nn2 + z * sh.g.Xr[rr][h];
        xout[(i0 + rr) * XS + h] = xo;
        sh.g.Xo[rr][h] = xo;
    }
    __syncthreads();

    // D: attention projections, 768 threads (w, q, h), 24-k partials
    if (tid < 768) {
        int h = tid % Hh;
        int q = (tid / Hh) & 3;
        int w = tid / 384;             // 0 = i-proj, 1 = j-proj
        const float* Wp = (w ? p.Wt_a1j : p.Wt_a1i) + h;
        float a0 = 0.f, a1 = 0.f, a2 = 0.f, a3 = 0.f;
        int k0 = q * 24;
#pragma unroll 4
        for (int k = k0; k < k0 + 24; ++k) {
            float wv = Wp[k * 96];
            a0 += sh.g.Xo[0][k] * wv;
            a1 += sh.g.Xo[1][k] * wv;
            a2 += sh.g.Xo[2][k] * wv;
            a3 += sh.g.Xo[3][k] * wv;
        }
        sh.g.redp[w][q][0][h] = a0;
        sh.g.redp[w][q][1][h] = a1;
        sh.g.redp[w][q][2][h] = a2;
        sh.g.redp[w][q][3][h] = a3;
    }
    __syncthreads();

    // E: finalize projections, 768 threads (w, r, h)
    if (tid < 768) {
        int h = tid % Hh;
        int rr = (tid / Hh) & 3;
        int w = tid / 384;
        int n = i0 + rr;
        float s = sh.g.redp[w][0][rr][h] + sh.g.redp[w][1][rr][h]
                + sh.g.redp[w][2][rr][h] + sh.g.redp[w][3][rr][h];
        if (w == 0) p.Ei[n * Hh + h]  = __expf(-(s + p.ba1[h]));
        else        p.EjT[h * Nn + n] = __expf(-s);
    }
    // no trailing block sync: a gsync follows
}

// ---------------- attn phases (unchanged hot code) --------------------------
__device__ __forceinline__ void attn_coeff(const Params& p, Shm& sh,
                                           const float* xB)
{
    int tid = threadIdx.x;
    int i0 = blockIdx.x * 4;
    {
        int j = tid;
        int m0 = p.adj[(i0 + 0) * Nn + j];
        int m1 = p.adj[(i0 + 1) * Nn + j];
        int m2 = p.adj[(i0 + 2) * Nn + j];
        int m3 = p.adj[(i0 + 3) * Nn + j];
        const float* e0 = p.Ei + i0 * Hh;   // uniform base -> s_load path
        float s0 = 0.f, s1 = 0.f, s2 = 0.f, s3 = 0.f;
#pragma unroll 8
        for (int k = 0; k < Hh; ++k) {
            float e = p.EjT[k * Nn + j];
            float wk = p.Wa2[k];            // s_load
            s0 += __builtin_amdgcn_rcpf(fmaf(e0[k], e, 1.0f)) * wk;
            s1 += __builtin_amdgcn_rcpf(fmaf(e0[96 + k], e, 1.0f)) * wk;
            s2 += __builtin_amdgcn_rcpf(fmaf(e0[192 + k], e, 1.0f)) * wk;
            s3 += __builtin_amdgcn_rcpf(fmaf(e0[288 + k], e, 1.0f)) * wk;
        }
        float b2 = p.ba2[0];
        sh.a.sm[0 * Nn + j] = (m0 == 1) ? sigf(s0 + b2) : 0.0f;
        sh.a.sm[1 * Nn + j] = (m1 == 1) ? sigf(s1 + b2) : 0.0f;
        sh.a.sm[2 * Nn + j] = (m2 == 1) ? sigf(s2 + b2) : 0.0f;
        sh.a.sm[3 * Nn + j] = (m3 == 1) ? sigf(s3 + b2) : 0.0f;
    }
    __syncthreads();
    {
        int q = tid >> 7;
        int h = tid & 127;
        if (h < Hh) {
            int jb = q * 128;
            const float* xc = xB + jb * XS + h;
            const float* c0 = sh.a.sm + 0 * Nn + jb;
            const float* c1 = sh.a.sm + 1 * Nn + jb;
            const float* c2 = sh.a.sm + 2 * Nn + jb;
            const float* c3 = sh.a.sm + 3 * Nn + jb;
            float a0 = 0.f, a1 = 0.f, a2 = 0.f, a3 = 0.f;
#pragma unroll 4
            for (int j = 0; j < 128; ++j) {
                float xv = xc[j * XS];
                a0 += c0[j] * xv;
                a1 += c1[j] * xv;
                a2 += c2[j] * xv;
                a3 += c3[j] * xv;
            }
            sh.a.sm[4096 + ((q * 4 + 0) * Hh) + h] = a0;
            sh.a.sm[4096 + ((q * 4 + 1) * Hh) + h] = a1;
            sh.a.sm[4096 + ((q * 4 + 2) * Hh) + h] = a2;
            sh.a.sm[4096 + ((q * 4 + 3) * Hh) + h] = a3;
        }
    }
    __syncthreads();
}

__device__ __forceinline__ void attn_tail_u0(const Params& p, Shm& sh,
                                             float* xOut)
{
    int tid = threadIdx.x;
    int i0 = blockIdx.x * 4;
    if (tid < 4 * Hh) {
        int r = tid / Hh, h = tid - r * Hh;
        float v = 0.f;
#pragma unroll
        for (int q = 0; q < 8; ++q)
            v += sh.a.sm[4096 + ((q * 4 + r) * Hh) + h];
        xOut[(i0 + r) * XS + h] = v;
    }
}

__device__ __forceinline__ void attn_tail_u1(const Params& p, Shm& sh)
{
    int tid = threadIdx.x;
    int i0 = blockIdx.x * 4;
    if (tid < 4 * Hh) {
        int r = tid / Hh, h = tid - r * Hh;
        float v = 0.f;
#pragma unroll
        for (int q = 0; q < 8; ++q)
            v += sh.a.sm[4096 + ((q * 4 + r) * Hh) + h];
        sh.a.hd[0][r][h] = v;
    }
    __syncthreads();
    if (tid < 4 * Hh) {
        int r = tid / Hh, h = tid - r * Hh;
        const float* w = p.Wt_o1 + h;
        const float* xr = sh.a.hd[0][r];
        float acc = p.bo1[h];
        for (int k = 0; k < Hh; ++k) acc += xr[k] * w[k * 96];
        sh.a.hd[1][r][h] = leakyf(acc);
    }
    __syncthreads();
    if (tid < 4 * Hh) {
        int r = tid / Hh, h = tid - r * Hh;
        const float* w = p.Wt_o2 + h;
        const float* xr = sh.a.hd[1][r];
        float acc = p.bo2[h];
        for (int k = 0; k < Hh; ++k) acc += xr[k] * w[k * 96];
        sh.a.hd[2][r][h] = leakyf(acc);
    }
    __syncthreads();
    if (tid < 8) {
        int r = tid >> 1, which = tid & 1;
        const float* wp = which ? p.Wp2 : p.Wp1;
        const float* xr = sh.a.hd[2][r];
        float acc = 0.f;
        for (int k = 0; k < Hh; ++k) acc += xr[k] * wp[k];
        float b = which ? p.bp2[0] : p.bp1[0];
        p.out[which * Nn + i0 + r] = sigf(acc + b);
    }
}

// ---------------- fused persistent kernel ----------------------------------
__global__ __launch_bounds__(1024) void fused_kernel(Params p)
{
    __shared__ Shm sh;
    int tid = threadIdx.x;
    int blk = blockIdx.x;

    // ---- P0: setup spread over ALL blocks; edges 64/block (deg pre-zeroed
    //      by host-side memset, global atomics — parallel, no serialization)
    {
        int gt = blk * 1024 + tid;          // [0, 262144) covers all work
        if (gt < 64512) {   // transposes: Wt_hh 27648 + 4x9216
            int idx = gt;
            if (idx < 27648) {
                int k = idx / 288, c = idx % 288;
                p.Wt_hh[idx] = p.W_hh[c * 96 + k];
            } else if ((idx -= 27648) < 9216) {
                int k = idx / 96, h2 = idx % 96;
                p.Wt_a1i[idx] = p.Wa1[h2 * 192 + k];
            } else if ((idx -= 9216) < 9216) {
                int k = idx / 96, h2 = idx % 96;
                p.Wt_a1j[idx] = p.Wa1[h2 * 192 + 96 + k];
            } else if ((idx -= 9216) < 9216) {
                int k = idx / 96, j = idx % 96;
                p.Wt_o1[idx] = p.Wo1[j * 96 + k];
            } else {
                idx -= 9216;
                int k = idx / 96, j = idx % 96;
                p.Wt_o2[idx] = p.Wo2[j * 96 + k];
            }
        }
        if (gt < 27648) {   // Wf[k][c] = sum_j W_ggc[k][j] * W_ih[c][j]
            int k = gt / 288, c = gt % 288;
            const float* g = p.W_ggc + k * 96;
            const float* w = p.W_ih + c * 96;
            float acc = 0.0f;
            for (int j = 0; j < 96; ++j) acc += g[j] * w[j];
            p.Wf[gt] = acc;
        }
        if (gt < NH) {      // init linear
            int n = gt / Hh, j = gt - n * Hh;
            const float* xr = p.x_in + n * IN_STRIDE;
            const float* wr = p.W_init + j * IN_K;
            float acc = p.b_init[j];
#pragma unroll
            for (int k = 0; k < IN_K; ++k) acc += xr[k] * wr[k];
            p.xA[n * XS + j] = leakyf(acc);
        }
        if (tid >= 960) {   // edges: 64 per block
            int e = blk * 64 + (tid - 960);
            int src = p.ei[e];
            int tgt = p.ei[Ee + e];
            int slot = atomicAdd(&p.deg[tgt], 1);
            if (slot < SLOTS) p.bucket[tgt * SLOTS + slot] = src;
        }
    }
    gsync(p.bar, 0);

    // ---- unroll 0: xA -> xB -> xC ----
    gru_phase(p, sh, p.xA, p.xB);
    gsync(p.bar, 1);
    attn_coeff(p, sh, p.xB);
    attn_tail_u0(p, sh, p.xC);
    gsync(p.bar, 2);

    // ---- unroll 1: xC -> xB -> (fused head) -> out ----
    gru_phase(p, sh, p.xC, p.xB);
    gsync(p.bar, 3);
    attn_coeff(p, sh, p.xB);
    attn_tail_u1(p, sh);
}

extern "C" void kernel_launch(void* const* d_in, const int* in_sizes, int n_in,
                              void* d_out, int out_size, void* d_ws, size_t ws_size,
                              hipStream_t stream)
{
    const float* x_in   = (const float*)d_in[0];
    const int*   ei     = (const int*)d_in[1];
    const int*   adj    = (const int*)d_in[2];
    const float* W_init = (const float*)d_in[3];
    const float* b_init = (const float*)d_in[4];
    const float* W_ggc  = (const float*)d_in[5];
    const float* W_ih   = (const float*)d_in[6];
    const float* W_hh   = (const float*)d_in[7];
    const float* b_ih   = (const float*)d_in[8];
    const float* b_hh   = (const float*)d_in[9];
    const float* Wa1    = (const float*)d_in[10];
    const float* ba1    = (const float*)d_in[11];
    const float* Wa2    = (const float*)d_in[12];
    const float* ba2    = (const float*)d_in[13];
    const float* Wo1    = (const float*)d_in[14];
    const float* bo1    = (const float*)d_in[15];
    const float* Wo2    = (const float*)d_in[16];
    const float* bo2    = (const float*)d_in[17];
    const float* Wp1    = (const float*)d_in[18];
    const float* bp1    = (const float*)d_in[19];
    const float* Wp2    = (const float*)d_in[20];
    const float* bp2    = (const float*)d_in[21];
    float* out = (float*)d_out;

    // workspace layout, ~3 MB
    float* ws     = (float*)d_ws;
    float* xA     = ws;                     // (N, XS)
    float* xB     = xA + Nn * XS;           // (N, XS)
    float* xC     = xB + Nn * XS;           // (N, XS)
    float* Ei     = xC + Nn * XS;           // (N, 96)
    float* EjT    = Ei + NH;                // (96, N)
    float* Wt_hh  = EjT + NH;               // 96*288
    float* Wf     = Wt_hh + 27648;          // 96*288
    float* Wt_a1i = Wf + 27648;             // 96*96
    float* Wt_a1j = Wt_a1i + 9216;
    float* Wt_o1  = Wt_a1j + 9216;
    float* Wt_o2  = Wt_o1 + 9216;
    int*   deg    = (int*)(Wt_o2 + 9216);   // (N) -- adjacent to bar: one memset
    int*   bar    = deg + Nn;               // 4 grid-barrier counters
    int*   bucket = bar + 4;                // (N, SLOTS)

    // zero deg + bar in one shot (deg must be re-zeroed every graph replay)
    hipMemsetAsync(deg, 0, (Nn + 4) * sizeof(int), stream);

    Params p;
    p.x_in = x_in; p.ei = ei; p.adj = adj;
    p.W_init = W_init; p.b_init = b_init;
    p.W_ggc = W_ggc; p.W_ih = W_ih; p.W_hh = W_hh;
    p.b_ih = b_ih; p.b_hh = b_hh;
    p.Wa1 = Wa1; p.ba1 = ba1; p.Wa2 = Wa2; p.ba2 = ba2;
    p.Wo1 = Wo1; p.bo1 = bo1; p.Wo2 = Wo2; p.bo2 = bo2;
    p.Wp1 = Wp1; p.bp1 = bp1; p.Wp2 = Wp2; p.bp2 = bp2;
    p.out = out;
    p.xA = xA; p.xB = xB; p.xC = xC; p.Ei = Ei; p.EjT = EjT;
    p.Wt_hh = Wt_hh; p.Wf = Wf; p.Wt_a1i = Wt_a1i; p.Wt_a1j = Wt_a1j;
    p.Wt_o1 = Wt_o1; p.Wt_o2 = Wt_o2;
    p.deg = deg; p.bucket = bucket; p.bar = bar;

    fused_kernel<<<NBLK, 1024, 0, stream>>>(p);
}

// Round 4
// 196.113 us; speedup vs baseline: 2.2898x; 1.4432x over previous
//
#include <hip/hip_runtime.h>

// Problem constants (from reference)
#define Nn 1024
#define Hh 96
#define Ee 16384
#define IN_K 9       // IN_RAW-1
#define IN_STRIDE 10 // x is (N, 10), we use first 9 cols
#define NH (Nn * Hh)
#define XS 128       // padded row stride for x-like (N,96) buffers
#define SLOTS 64     // CSR bucket capacity (Poisson(16) degree; P(>64) ~ 0)

__device__ __forceinline__ float sigf(float v) {
    return __builtin_amdgcn_rcpf(1.0f + __expf(-v));
}
__device__ __forceinline__ float tanhfast(float v) {
    float e = __expf(2.0f * v);
    return (e - 1.0f) * __builtin_amdgcn_rcpf(e + 1.0f);
}
__device__ __forceinline__ float leakyf(float v) {
    return v >= 0.0f ? v : 0.01f * v;
}

// ---------------- K0: setup (transposes + Wf fold + init linear) + edges ---
// grid 256 x 1024. deg pre-zeroed by host memset; edge scatter parallel
// across all blocks (64 edges/block, tid>=960).
__global__ __launch_bounds__(1024) void setup_kernel(
    const float* __restrict__ W_hh, const float* __restrict__ Wa1,
    const float* __restrict__ Wo1, const float* __restrict__ Wo2,
    const float* __restrict__ W_ggc, const float* __restrict__ W_ih,
    const float* __restrict__ x_in, const float* __restrict__ W_init,
    const float* __restrict__ b_init, const int* __restrict__ ei,
    float* __restrict__ Wt_hh, float* __restrict__ Wt_a1i,
    float* __restrict__ Wt_a1j, float* __restrict__ Wt_o1,
    float* __restrict__ Wt_o2, float* __restrict__ Wf,
    float* __restrict__ xA, int* __restrict__ deg, int* __restrict__ bucket)
{
    int tid = threadIdx.x;
    int blk = blockIdx.x;
    int gt = blk * 1024 + tid;
    if (gt < 64512) {   // transposes: Wt_hh 27648 + 4x9216
        int idx = gt;
        if (idx < 27648) {
            int k = idx / 288, c = idx % 288;
            Wt_hh[idx] = W_hh[c * 96 + k];
        } else if ((idx -= 27648) < 9216) {
            int k = idx / 96, h2 = idx % 96;
            Wt_a1i[idx] = Wa1[h2 * 192 + k];
        } else if ((idx -= 9216) < 9216) {
            int k = idx / 96, h2 = idx % 96;
            Wt_a1j[idx] = Wa1[h2 * 192 + 96 + k];
        } else if ((idx -= 9216) < 9216) {
            int k = idx / 96, j = idx % 96;
            Wt_o1[idx] = Wo1[j * 96 + k];
        } else {
            idx -= 9216;
            int k = idx / 96, j = idx % 96;
            Wt_o2[idx] = Wo2[j * 96 + k];
        }
    }
    if (gt < 27648) {   // Wf[k][c] = sum_j W_ggc[k][j] * W_ih[c][j]
        int k = gt / 288, c = gt % 288;
        const float* g = W_ggc + k * 96;
        const float* w = W_ih + c * 96;
        float acc = 0.0f;
        for (int j = 0; j < 96; ++j) acc += g[j] * w[j];
        Wf[gt] = acc;
    }
    if (gt < NH) {      // init linear
        int n = gt / Hh, j = gt - n * Hh;
        const float* xr = x_in + n * IN_STRIDE;
        const float* wr = W_init + j * IN_K;
        float acc = b_init[j];
#pragma unroll
        for (int k = 0; k < IN_K; ++k) acc += xr[k] * wr[k];
        xA[n * XS + j] = leakyf(acc);
    }
    if (tid >= 960) {   // edges: 64 per block, 256 blocks = 16384
        int e = blk * 64 + (tid - 960);
        int src = ei[e];
        int tgt = ei[Ee + e];
        int slot = atomicAdd(&deg[tgt], 1);
        if (slot < SLOTS) bucket[tgt * SLOTS + slot] = src;
    }
}

// ---------------- K1/K3: gru, 4 rows/block, 768 threads --------------------
// Weight-register-sharing: each weight load feeds 4 rows. Gate dots are
// full-K per thread (no k-split reduction round-trip). LDS 29184 B.
struct GShm {
    float Pg[2][4][Hh];         // gather split-2 partials
    float Pm[4][Hh];            // per-row gather mean
    float Xr[4][Hh];            // per-row x
    float Xo[4][Hh];            // per-row GRU output
    float gd[6][4][Hh];         // full-K gate dots [gate][row][h]
    float redp[2][4][4][Hh];    // proj partials [w][q][row][h]
};

__global__ __launch_bounds__(768) void gru_kernel(
    const float* __restrict__ xin, const int* __restrict__ deg,
    const int* __restrict__ bucket,
    const float* __restrict__ Wf, const float* __restrict__ Wt_hh,
    const float* __restrict__ b_ih, const float* __restrict__ b_hh,
    const float* __restrict__ Wt_a1i, const float* __restrict__ Wt_a1j,
    const float* __restrict__ ba1,
    float* __restrict__ xout, float* __restrict__ Ei, float* __restrict__ EjT)
{
    __shared__ GShm sh;
    int tid = threadIdx.x;
    int i0 = blockIdx.x * 4;

    // A: gather, 768 threads (s2, r, h); thread sums slots s2, s2+2, ...
    {
        int h = tid % Hh;
        int rr = (tid / Hh) & 3;
        int s2 = tid / 384;
        int n = i0 + rr;
        int d = deg[n];
        int dc = d < SLOTS ? d : SLOTS;
        const int* bk = bucket + n * SLOTS;
        float acc = 0.0f;
        for (int s = s2; s < dc; s += 2)
            acc += xin[bk[s] * XS + h];
        sh.Pg[s2][rr][h] = acc;
        if (s2 == 0) sh.Xr[rr][h] = xin[n * XS + h];
    }
    __syncthreads();
    if (tid < 384) {   // combine -> mean
        int h = tid % Hh, rr = tid / Hh;
        float inv = __builtin_amdgcn_rcpf(fmaxf((float)deg[i0 + rr], 1.0f));
        sh.Pm[rr][h] = (sh.Pg[0][rr][h] + sh.Pg[1][rr][h]) * inv;
    }
    __syncthreads();

    // B: 6 gate dots, 576 threads (gate, h), full K=96, 4 rows in registers
    if (tid < 576) {
        int h = tid % Hh;
        int g = tid / Hh;              // 0..2: i-path (Wf/Pm), 3..5: h-path
        bool ipath = g < 3;
        int gc = ipath ? g : g - 3;
        const float* W = (ipath ? Wf : Wt_hh) + gc * 96 + h;
        const float (*src)[Hh] = ipath ? sh.Pm : sh.Xr;
        float a0 = 0.f, a1 = 0.f, a2 = 0.f, a3 = 0.f;
#pragma unroll 8
        for (int k = 0; k < 96; ++k) {
            float w = W[k * 288];
            a0 += src[0][k] * w;
            a1 += src[1][k] * w;
            a2 += src[2][k] * w;
            a3 += src[3][k] * w;
        }
        sh.gd[g][0][h] = a0;
        sh.gd[g][1][h] = a1;
        sh.gd[g][2][h] = a2;
        sh.gd[g][3][h] = a3;
    }
    __syncthreads();

    // C: gate math, 384 threads (r, h)
    if (tid < 384) {
        int h = tid % Hh, rr = tid / Hh;
        float gir = b_ih[h]        + sh.gd[0][rr][h];
        float giz = b_ih[96 + h]   + sh.gd[1][rr][h];
        float gin = b_ih[192 + h]  + sh.gd[2][rr][h];
        float ghr = b_hh[h]        + sh.gd[3][rr][h];
        float ghz = b_hh[96 + h]   + sh.gd[4][rr][h];
        float ghn = b_hh[192 + h]  + sh.gd[5][rr][h];
        float r_  = sigf(gir + ghr);
        float z   = sigf(giz + ghz);
        float nn2 = tanhfast(gin + r_ * ghn);
        float xo  = (1.0f - z) * nn2 + z * sh.Xr[rr][h];
        xout[(i0 + rr) * XS + h] = xo;
        sh.Xo[rr][h] = xo;
    }
    __syncthreads();

    // D: attention projections, 768 threads (w, q, h), 24-k partials
    {
        int h = tid % Hh;
        int q = (tid / Hh) & 3;
        int w = tid / 384;             // 0 = i-proj, 1 = j-proj
        const float* Wp = (w ? Wt_a1j : Wt_a1i) + h;
        float a0 = 0.f, a1 = 0.f, a2 = 0.f, a3 = 0.f;
        int k0 = q * 24;
#pragma unroll 4
        for (int k = k0; k < k0 + 24; ++k) {
            float wv = Wp[k * 96];
            a0 += sh.Xo[0][k] * wv;
            a1 += sh.Xo[1][k] * wv;
            a2 += sh.Xo[2][k] * wv;
            a3 += sh.Xo[3][k] * wv;
        }
        sh.redp[w][q][0][h] = a0;
        sh.redp[w][q][1][h] = a1;
        sh.redp[w][q][2][h] = a2;
        sh.redp[w][q][3][h] = a3;
    }
    __syncthreads();

    // E: finalize projections, 768 threads (w, r, h)
    {
        int h = tid % Hh;
        int rr = (tid / Hh) & 3;
        int w = tid / 384;
        int n = i0 + rr;
        float s = sh.redp[w][0][rr][h] + sh.redp[w][1][rr][h]
                + sh.redp[w][2][rr][h] + sh.redp[w][3][rr][h];
        if (w == 0) Ei[n * Hh + h]  = __expf(-(s + ba1[h]));
        else        EjT[h * Nn + n] = __expf(-s);
    }
}

// ---------------- K2: attn unroll 0 ----------------------------------------
// 4 rows x full j per block. Ei rows + Wa2 staged in LDS (broadcast reads).
__global__ __launch_bounds__(1024) void attn_kernel_u0(
    const float* __restrict__ Ei, const float* __restrict__ EjT,
    const float* __restrict__ Wa2, const float* __restrict__ ba2,
    const int* __restrict__ adj, const float* __restrict__ xB,
    float* __restrict__ xOut)
{
    __shared__ float sm[7168];
    __shared__ float eis[4 * Hh];
    __shared__ float wa2s[Hh];
    int tid = threadIdx.x;
    int i0 = blockIdx.x * 4;
    if (tid < 4 * Hh) eis[tid] = Ei[i0 * Hh + tid];
    if (tid >= 512 && tid < 512 + Hh) wa2s[tid - 512] = Wa2[tid - 512];
    {
        int j = tid;
        int m0 = adj[(i0 + 0) * Nn + j];
        int m1 = adj[(i0 + 1) * Nn + j];
        int m2 = adj[(i0 + 2) * Nn + j];
        int m3 = adj[(i0 + 3) * Nn + j];
        __syncthreads();
        float s0 = 0.f, s1 = 0.f, s2 = 0.f, s3 = 0.f;
#pragma unroll 8
        for (int k = 0; k < Hh; ++k) {
            float e = EjT[k * Nn + j];
            float wk = wa2s[k];                // LDS broadcast
            s0 += __builtin_amdgcn_rcpf(fmaf(eis[k], e, 1.0f)) * wk;
            s1 += __builtin_amdgcn_rcpf(fmaf(eis[96 + k], e, 1.0f)) * wk;
            s2 += __builtin_amdgcn_rcpf(fmaf(eis[192 + k], e, 1.0f)) * wk;
            s3 += __builtin_amdgcn_rcpf(fmaf(eis[288 + k], e, 1.0f)) * wk;
        }
        float b2 = ba2[0];
        sm[0 * Nn + j] = (m0 == 1) ? sigf(s0 + b2) : 0.0f;
        sm[1 * Nn + j] = (m1 == 1) ? sigf(s1 + b2) : 0.0f;
        sm[2 * Nn + j] = (m2 == 1) ? sigf(s2 + b2) : 0.0f;
        sm[3 * Nn + j] = (m3 == 1) ? sigf(s3 + b2) : 0.0f;
    }
    __syncthreads();
    {
        int q = tid >> 7;
        int h = tid & 127;
        if (h < Hh) {
            int jb = q * 128;
            const float* xc = xB + jb * XS + h;
            const float* c0 = sm + 0 * Nn + jb;
            const float* c1 = sm + 1 * Nn + jb;
            const float* c2 = sm + 2 * Nn + jb;
            const float* c3 = sm + 3 * Nn + jb;
            float a0 = 0.f, a1 = 0.f, a2 = 0.f, a3 = 0.f;
#pragma unroll 4
            for (int j = 0; j < 128; ++j) {
                float xv = xc[j * XS];
                a0 += c0[j] * xv;
                a1 += c1[j] * xv;
                a2 += c2[j] * xv;
                a3 += c3[j] * xv;
            }
            sm[4096 + ((q * 4 + 0) * Hh) + h] = a0;
            sm[4096 + ((q * 4 + 1) * Hh) + h] = a1;
            sm[4096 + ((q * 4 + 2) * Hh) + h] = a2;
            sm[4096 + ((q * 4 + 3) * Hh) + h] = a3;
        }
    }
    __syncthreads();
    if (tid < 4 * Hh) {
        int r = tid / Hh, h = tid - r * Hh;
        float v = 0.f;
#pragma unroll
        for (int q = 0; q < 8; ++q)
            v += sm[4096 + ((q * 4 + r) * Hh) + h];
        xOut[(i0 + r) * XS + h] = v;
    }
}

// ---------------- K4: attn unroll 1 + fused output head --------------------
__global__ __launch_bounds__(1024) void attn_kernel_u1(
    const float* __restrict__ Ei, const float* __restrict__ EjT,
    const float* __restrict__ Wa2, const float* __restrict__ ba2,
    const int* __restrict__ adj, const float* __restrict__ xB,
    const float* __restrict__ Wt_o1, const float* __restrict__ bo1,
    const float* __restrict__ Wt_o2, const float* __restrict__ bo2,
    const float* __restrict__ Wp1, const float* __restrict__ bp1,
    const float* __restrict__ Wp2, const float* __restrict__ bp2,
    float* __restrict__ out)
{
    __shared__ float sm[7168];
    __shared__ float eis[4 * Hh];
    __shared__ float wa2s[Hh];
    __shared__ float hd[3][4][Hh];    // xout, t1, t2 for the fused head
    int tid = threadIdx.x;
    int i0 = blockIdx.x * 4;
    if (tid < 4 * Hh) eis[tid] = Ei[i0 * Hh + tid];
    if (tid >= 512 && tid < 512 + Hh) wa2s[tid - 512] = Wa2[tid - 512];
    {
        int j = tid;
        int m0 = adj[(i0 + 0) * Nn + j];
        int m1 = adj[(i0 + 1) * Nn + j];
        int m2 = adj[(i0 + 2) * Nn + j];
        int m3 = adj[(i0 + 3) * Nn + j];
        __syncthreads();
        float s0 = 0.f, s1 = 0.f, s2 = 0.f, s3 = 0.f;
#pragma unroll 8
        for (int k = 0; k < Hh; ++k) {
            float e = EjT[k * Nn + j];
            float wk = wa2s[k];                // LDS broadcast
            s0 += __builtin_amdgcn_rcpf(fmaf(eis[k], e, 1.0f)) * wk;
            s1 += __builtin_amdgcn_rcpf(fmaf(eis[96 + k], e, 1.0f)) * wk;
            s2 += __builtin_amdgcn_rcpf(fmaf(eis[192 + k], e, 1.0f)) * wk;
            s3 += __builtin_amdgcn_rcpf(fmaf(eis[288 + k], e, 1.0f)) * wk;
        }
        float b2 = ba2[0];
        sm[0 * Nn + j] = (m0 == 1) ? sigf(s0 + b2) : 0.0f;
        sm[1 * Nn + j] = (m1 == 1) ? sigf(s1 + b2) : 0.0f;
        sm[2 * Nn + j] = (m2 == 1) ? sigf(s2 + b2) : 0.0f;
        sm[3 * Nn + j] = (m3 == 1) ? sigf(s3 + b2) : 0.0f;
    }
    __syncthreads();
    {
        int q = tid >> 7;
        int h = tid & 127;
        if (h < Hh) {
            int jb = q * 128;
            const float* xc = xB + jb * XS + h;
            const float* c0 = sm + 0 * Nn + jb;
            const float* c1 = sm + 1 * Nn + jb;
            const float* c2 = sm + 2 * Nn + jb;
            const float* c3 = sm + 3 * Nn + jb;
            float a0 = 0.f, a1 = 0.f, a2 = 0.f, a3 = 0.f;
#pragma unroll 4
            for (int j = 0; j < 128; ++j) {
                float xv = xc[j * XS];
                a0 += c0[j] * xv;
                a1 += c1[j] * xv;
                a2 += c2[j] * xv;
                a3 += c3[j] * xv;
            }
            sm[4096 + ((q * 4 + 0) * Hh) + h] = a0;
            sm[4096 + ((q * 4 + 1) * Hh) + h] = a1;
            sm[4096 + ((q * 4 + 2) * Hh) + h] = a2;
            sm[4096 + ((q * 4 + 3) * Hh) + h] = a3;
        }
    }
    __syncthreads();
    if (tid < 4 * Hh) {
        int r = tid / Hh, h = tid - r * Hh;
        float v = 0.f;
#pragma unroll
        for (int q = 0; q < 8; ++q)
            v += sm[4096 + ((q * 4 + r) * Hh) + h];
        hd[0][r][h] = v;
    }
    __syncthreads();
    if (tid < 4 * Hh) {
        int r = tid / Hh, h = tid - r * Hh;
        const float* w = Wt_o1 + h;
        const float* xr = hd[0][r];
        float acc = bo1[h];
        for (int k = 0; k < Hh; ++k) acc += xr[k] * w[k * 96];
        hd[1][r][h] = leakyf(acc);
    }
    __syncthreads();
    if (tid < 4 * Hh) {
        int r = tid / Hh, h = tid - r * Hh;
        const float* w = Wt_o2 + h;
        const float* xr = hd[1][r];
        float acc = bo2[h];
        for (int k = 0; k < Hh; ++k) acc += xr[k] * w[k * 96];
        hd[2][r][h] = leakyf(acc);
    }
    __syncthreads();
    if (tid < 8) {
        int r = tid >> 1, which = tid & 1;
        const float* wp = which ? Wp2 : Wp1;
        const float* xr = hd[2][r];
        float acc = 0.f;
        for (int k = 0; k < Hh; ++k) acc += xr[k] * wp[k];
        float b = which ? bp2[0] : bp1[0];
        out[which * Nn + i0 + r] = sigf(acc + b);
    }
}

extern "C" void kernel_launch(void* const* d_in, const int* in_sizes, int n_in,
                              void* d_out, int out_size, void* d_ws, size_t ws_size,
                              hipStream_t stream)
{
    const float* x_in   = (const float*)d_in[0];
    const int*   ei     = (const int*)d_in[1];
    const int*   adj    = (const int*)d_in[2];
    const float* W_init = (const float*)d_in[3];
    const float* b_init = (const float*)d_in[4];
    const float* W_ggc  = (const float*)d_in[5];
    const float* W_ih   = (const float*)d_in[6];
    const float* W_hh   = (const float*)d_in[7];
    const float* b_ih   = (const float*)d_in[8];
    const float* b_hh   = (const float*)d_in[9];
    const float* Wa1    = (const float*)d_in[10];
    const float* ba1    = (const float*)d_in[11];
    const float* Wa2    = (const float*)d_in[12];
    const float* ba2    = (const float*)d_in[13];
    const float* Wo1    = (const float*)d_in[14];
    const float* bo1    = (const float*)d_in[15];
    const float* Wo2    = (const float*)d_in[16];
    const float* bo2    = (const float*)d_in[17];
    const float* Wp1    = (const float*)d_in[18];
    const float* bp1    = (const float*)d_in[19];
    const float* Wp2    = (const float*)d_in[20];
    const float* bp2    = (const float*)d_in[21];
    float* out = (float*)d_out;

    // workspace layout, ~3 MB
    float* ws     = (float*)d_ws;
    float* xA     = ws;                     // (N, XS)
    float* xB     = xA + Nn * XS;           // (N, XS)
    float* xC     = xB + Nn * XS;           // (N, XS)
    float* Ei     = xC + Nn * XS;           // (N, 96)
    float* EjT    = Ei + NH;                // (96, N)
    float* Wt_hh  = EjT + NH;               // 96*288
    float* Wf     = Wt_hh + 27648;          // 96*288
    float* Wt_a1i = Wf + 27648;             // 96*96
    float* Wt_a1j = Wt_a1i + 9216;
    float* Wt_o1  = Wt_a1j + 9216;
    float* Wt_o2  = Wt_o1 + 9216;
    int*   deg    = (int*)(Wt_o2 + 9216);   // (N)
    int*   bucket = deg + Nn;               // (N, SLOTS)

    // deg must be re-zeroed every graph replay (edge scatter atomics)
    hipMemsetAsync(deg, 0, Nn * sizeof(int), stream);

    setup_kernel<<<256, 1024, 0, stream>>>(
        W_hh, Wa1, Wo1, Wo2, W_ggc, W_ih, x_in, W_init, b_init, ei,
        Wt_hh, Wt_a1i, Wt_a1j, Wt_o1, Wt_o2, Wf, xA, deg, bucket);

    // unroll 0: xA -> xB -> xC
    gru_kernel<<<256, 768, 0, stream>>>(
        xA, deg, bucket, Wf, Wt_hh, b_ih, b_hh, Wt_a1i, Wt_a1j, ba1,
        xB, Ei, EjT);
    attn_kernel_u0<<<256, 1024, 0, stream>>>(
        Ei, EjT, Wa2, ba2, adj, xB, xC);

    // unroll 1: xC -> xB -> (head fused) -> out
    gru_kernel<<<256, 768, 0, stream>>>(
        xC, deg, bucket, Wf, Wt_hh, b_ih, b_hh, Wt_a1i, Wt_a1j, ba1,
        xB, Ei, EjT);
    attn_kernel_u1<<<256, 1024, 0, stream>>>(
        Ei, EjT, Wa2, ba2, adj, xB,
        Wt_o1, bo1, Wt_o2, bo2, Wp1, bp1, Wp2, bp2, out);
}